// Round 4
// baseline (3402.841 us; speedup 1.0000x reference)
//
#include <hip/hip_runtime.h>
#include <hip/hip_bf16.h>

// GCN 3-layer forward: x[N,128] -> GCNConv(64) -> leaky -> GCNConv(32) -> leaky
// -> GCNConv(4) -> softmax.  N=100000, E=3200000.
// norm: deg[i] = 1 + sum_{e: dst=i} w[e]; dis = rsqrt(deg);
// conv: out[d] = sum_e dis[s]*w*dis[d]*h[s] + dis[d]^2*h[d]  (self loop), + bias after.

#define BLK 256

__global__ void k_init_deg(float* __restrict__ deg, int n) {
    int i = blockIdx.x * blockDim.x + threadIdx.x;
    if (i < n) deg[i] = 1.0f;   // self-loop weight
}

__global__ void k_deg_edges(const int* __restrict__ dst, const float* __restrict__ w,
                            float* __restrict__ deg, int E) {
    int e = blockIdx.x * blockDim.x + threadIdx.x;
    if (e < E) atomicAdd(&deg[dst[e]], w[e]);
}

__global__ void k_finish_dis(float* __restrict__ deg, int n) {
    int i = blockIdx.x * blockDim.x + threadIdx.x;
    if (i < n) {
        float d = deg[i];
        deg[i] = d > 0.f ? rsqrtf(d) : 0.f;
    }
}

// out[n][c] = sum_k act(in[n][k]) * W[c][k];  act = (x+b_in) leaky if ACT.
template<int FIN, int FOUT, bool ACT>
__global__ void k_linear(const float* __restrict__ in, const float* __restrict__ W,
                         const float* __restrict__ bias_in, float* __restrict__ out, int n) {
    __shared__ float Ws[FOUT * FIN];
    __shared__ float bs[FIN];
    for (int i = threadIdx.x; i < FOUT * FIN; i += blockDim.x) Ws[i] = W[i];
    if (ACT) for (int i = threadIdx.x; i < FIN; i += blockDim.x) bs[i] = bias_in[i];
    __syncthreads();
    int nidx = blockIdx.x * blockDim.x + threadIdx.x;
    if (nidx >= n) return;
    float acc[FOUT];
#pragma unroll
    for (int c = 0; c < FOUT; ++c) acc[c] = 0.f;
    const float* row = in + (size_t)nidx * FIN;
#pragma unroll 4
    for (int k = 0; k < FIN; ++k) {
        float xv = row[k];
        if (ACT) {
            xv += bs[k];
            xv = xv > 0.f ? xv : 0.01f * xv;
        }
#pragma unroll
        for (int c = 0; c < FOUT; ++c) acc[c] += xv * Ws[c * FIN + k];
    }
    float* o = out + (size_t)nidx * FOUT;
#pragma unroll
    for (int c = 0; c < FOUT; ++c) o[c] = acc[c];
}

// agg[n][c] = dis[n]^2 * h[n][c]   (self-loop term; also initializes agg)
template<int F>
__global__ void k_selfloop(const float* __restrict__ h, const float* __restrict__ dis,
                           float* __restrict__ agg, int n) {
    int gid = blockIdx.x * blockDim.x + threadIdx.x;
    if (gid >= n * F) return;
    int node = gid / F;
    float d = dis[node];
    agg[gid] = d * d * h[gid];
}

// one thread per (edge, col): agg[dst][c] += dis[src]*w*dis[dst] * h[src][c]
template<int F>
__global__ void k_scatter(const int* __restrict__ src, const int* __restrict__ dst,
                          const float* __restrict__ w, const float* __restrict__ dis,
                          const float* __restrict__ h, float* __restrict__ agg, int E) {
    int gid = blockIdx.x * blockDim.x + threadIdx.x;
    if (gid >= E * F) return;          // E*F max 204.8M < 2^31
    int e = gid / F;
    int c = gid & (F - 1);
    int s = src[e], d = dst[e];
    float coef = dis[s] * w[e] * dis[d];
    atomicAdd(&agg[(size_t)d * F + c], coef * h[(size_t)s * F + c]);
}

__global__ void k_softmax4(const float* __restrict__ agg, const float* __restrict__ b,
                           float* __restrict__ out, int n) {
    int i = blockIdx.x * blockDim.x + threadIdx.x;
    if (i >= n) return;
    float b0 = b[0], b1 = b[1], b2 = b[2], b3 = b[3];
    float v0 = agg[i * 4 + 0] + b0;
    float v1 = agg[i * 4 + 1] + b1;
    float v2 = agg[i * 4 + 2] + b2;
    float v3 = agg[i * 4 + 3] + b3;
    float m = fmaxf(fmaxf(v0, v1), fmaxf(v2, v3));
    float e0 = expf(v0 - m), e1 = expf(v1 - m), e2 = expf(v2 - m), e3 = expf(v3 - m);
    float inv = 1.f / (e0 + e1 + e2 + e3);
    out[i * 4 + 0] = e0 * inv;
    out[i * 4 + 1] = e1 * inv;
    out[i * 4 + 2] = e2 * inv;
    out[i * 4 + 3] = e3 * inv;
}

static inline int cdiv(long long a, int b) { return (int)((a + b - 1) / b); }

extern "C" void kernel_launch(void* const* d_in, const int* in_sizes, int n_in,
                              void* d_out, int out_size, void* d_ws, size_t ws_size,
                              hipStream_t stream) {
    const float* x   = (const float*)d_in[0];
    const int*   ei  = (const int*)d_in[1];
    const float* ew  = (const float*)d_in[2];
    const float* W1  = (const float*)d_in[3];
    const float* b1  = (const float*)d_in[4];
    const float* W2  = (const float*)d_in[5];
    const float* b2  = (const float*)d_in[6];
    const float* W3  = (const float*)d_in[7];
    const float* b3  = (const float*)d_in[8];
    float* out = (float*)d_out;

    const int N = in_sizes[0] / 128;
    const int E = in_sizes[2];
    const int* src = ei;
    const int* dst = ei + E;

    float* dis  = (float*)d_ws;          // N
    float* bufA = dis + N;               // N*64
    float* bufB = bufA + (size_t)N * 64; // N*64

    // --- normalization ---
    k_init_deg<<<cdiv(N, BLK), BLK, 0, stream>>>(dis, N);
    k_deg_edges<<<cdiv(E, BLK), BLK, 0, stream>>>(dst, ew, dis, E);
    k_finish_dis<<<cdiv(N, BLK), BLK, 0, stream>>>(dis, N);

    // --- layer 1: x[N,128] -> h1[N,64] ---
    k_linear<128, 64, false><<<cdiv(N, BLK), BLK, 0, stream>>>(x, W1, nullptr, bufA, N);
    k_selfloop<64><<<cdiv((long long)N * 64, BLK), BLK, 0, stream>>>(bufA, dis, bufB, N);
    k_scatter<64><<<cdiv((long long)E * 64, BLK), BLK, 0, stream>>>(src, dst, ew, dis, bufA, bufB, E);

    // --- layer 2: leaky(agg1+b1)[N,64] -> h2[N,32] ---
    k_linear<64, 32, true><<<cdiv(N, BLK), BLK, 0, stream>>>(bufB, W2, b1, bufA, N);
    k_selfloop<32><<<cdiv((long long)N * 32, BLK), BLK, 0, stream>>>(bufA, dis, bufB, N);
    k_scatter<32><<<cdiv((long long)E * 32, BLK), BLK, 0, stream>>>(src, dst, ew, dis, bufA, bufB, E);

    // --- layer 3: leaky(agg2+b2)[N,32] -> h3[N,4] ---
    k_linear<32, 4, true><<<cdiv(N, BLK), BLK, 0, stream>>>(bufB, W3, b2, bufA, N);
    k_selfloop<4><<<cdiv((long long)N * 4, BLK), BLK, 0, stream>>>(bufA, dis, bufB, N);
    k_scatter<4><<<cdiv((long long)E * 4, BLK), BLK, 0, stream>>>(src, dst, ew, dis, bufA, bufB, E);

    k_softmax4<<<cdiv(N, BLK), BLK, 0, stream>>>(bufB, b3, out, N);
}

// Round 7
// 1463.410 us; speedup vs baseline: 2.3253x; 2.3253x over previous
//
#include <hip/hip_runtime.h>
#include <hip/hip_bf16.h>

// GCN 3-layer forward: x[N,128] -> GCNConv(64) -> leaky -> GCNConv(32) -> leaky
// -> GCNConv(4) -> softmax.  N=100000, E=3200000.
// Round 5: k_linear rewritten as LDS-tiled GEMM (round-4 version spilled acc[] to
// scratch -> 8.6 GB of HBM traffic, 2 ms). Scatter untouched for clean attribution.

#define BLK 256

__global__ void k_init_deg(float* __restrict__ deg, int n) {
    int i = blockIdx.x * blockDim.x + threadIdx.x;
    if (i < n) deg[i] = 1.0f;   // self-loop weight
}

__global__ void k_deg_edges(const int* __restrict__ dst, const float* __restrict__ w,
                            float* __restrict__ deg, int E) {
    int e = blockIdx.x * blockDim.x + threadIdx.x;
    if (e < E) atomicAdd(&deg[dst[e]], w[e]);
}

__global__ void k_finish_dis(float* __restrict__ deg, int n) {
    int i = blockIdx.x * blockDim.x + threadIdx.x;
    if (i < n) {
        float d = deg[i];
        deg[i] = d > 0.f ? rsqrtf(d) : 0.f;
    }
}

__device__ __forceinline__ float leaky01(float v) {
    return v > 0.f ? v : 0.01f * v;
}

// Tiled linear: out[n][c] = sum_k act(in[n][k]) * W[c][k], act = leaky(x + bias_in).
// Block: 256 threads, 64-node tile. 4 threads per node, CPT = FOUT/4 cols each.
// LDS: Wt[k][c] (transposed weights) + xst[k][node] (transposed inputs).
template<int FIN, int FOUT, bool ACT>
__global__ __launch_bounds__(256) void k_linear(
        const float* __restrict__ in, const float* __restrict__ W,
        const float* __restrict__ bias_in, float* __restrict__ out, int n) {
    constexpr int TM = 64;            // nodes per block
    constexpr int CPT = FOUT / 4;     // columns per thread (16 / 8 / 1)
    __shared__ __align__(16) float Wt[FIN * FOUT];   // Wt[k*FOUT + c]
    __shared__ __align__(16) float xst[TM * FIN];    // xst[k*TM + node]

    const int tid = threadIdx.x;
    const int nb = blockIdx.x * TM;

    // stage W transposed (coalesced global read; LDS write conflicts are one-time)
    for (int i = tid; i < FIN * FOUT; i += 256) {
        int c = i / FIN, k = i % FIN;
        Wt[k * FOUT + c] = W[i];
    }
    __syncthreads();

    // stage x transposed, activation fused (bias from global, L1-resident)
    for (int i4 = tid; i4 < TM * FIN / 4; i4 += 256) {
        int idx = i4 * 4;
        int r = idx / FIN, k0 = idx % FIN;
        if (nb + r < n) {
            float4 v = *(const float4*)&in[(size_t)(nb + r) * FIN + k0];
            if (ACT) {
                float4 b = *(const float4*)&bias_in[k0];
                v.x = leaky01(v.x + b.x); v.y = leaky01(v.y + b.y);
                v.z = leaky01(v.z + b.z); v.w = leaky01(v.w + b.w);
            }
            xst[(k0 + 0) * TM + r] = v.x;
            xst[(k0 + 1) * TM + r] = v.y;
            xst[(k0 + 2) * TM + r] = v.z;
            xst[(k0 + 3) * TM + r] = v.w;
        }
    }
    __syncthreads();

    const int nl = tid >> 2;          // local node 0..63
    const int c0 = (tid & 3) * CPT;   // column range start
    if (nb + nl >= n) return;

    if constexpr (CPT >= 4) {
        float4 acc[CPT / 4];
#pragma unroll
        for (int j = 0; j < CPT / 4; ++j) acc[j] = make_float4(0.f, 0.f, 0.f, 0.f);
#pragma unroll 8
        for (int k = 0; k < FIN; ++k) {
            float xv = xst[k * TM + nl];
            const float4* wr = (const float4*)&Wt[k * FOUT + c0];
#pragma unroll
            for (int j = 0; j < CPT / 4; ++j) {
                float4 w4 = wr[j];
                acc[j].x += xv * w4.x; acc[j].y += xv * w4.y;
                acc[j].z += xv * w4.z; acc[j].w += xv * w4.w;
            }
        }
        float4* o = (float4*)&out[(size_t)(nb + nl) * FOUT + c0];
#pragma unroll
        for (int j = 0; j < CPT / 4; ++j) o[j] = acc[j];
    } else {  // CPT == 1 (FOUT == 4)
        float acc = 0.f;
#pragma unroll 8
        for (int k = 0; k < FIN; ++k)
            acc += xst[k * TM + nl] * Wt[k * FOUT + c0];
        out[(size_t)(nb + nl) * FOUT + c0] = acc;
    }
}

// agg[n][c] = dis[n]^2 * h[n][c]   (self-loop term; also initializes agg)
template<int F>
__global__ void k_selfloop(const float* __restrict__ h, const float* __restrict__ dis,
                           float* __restrict__ agg, int n) {
    int gid = blockIdx.x * blockDim.x + threadIdx.x;
    if (gid >= n * F) return;
    int node = gid / F;
    float d = dis[node];
    agg[gid] = d * d * h[gid];
}

// one thread per (edge, col): agg[dst][c] += dis[src]*w*dis[dst] * h[src][c]
template<int F>
__global__ void k_scatter(const int* __restrict__ src, const int* __restrict__ dst,
                          const float* __restrict__ w, const float* __restrict__ dis,
                          const float* __restrict__ h, float* __restrict__ agg, int E) {
    int gid = blockIdx.x * blockDim.x + threadIdx.x;
    if (gid >= E * F) return;          // E*F max 204.8M < 2^31
    int e = gid / F;
    int c = gid & (F - 1);
    int s = src[e], d = dst[e];
    float coef = dis[s] * w[e] * dis[d];
    atomicAdd(&agg[(size_t)d * F + c], coef * h[(size_t)s * F + c]);
}

__global__ void k_softmax4(const float* __restrict__ agg, const float* __restrict__ b,
                           float* __restrict__ out, int n) {
    int i = blockIdx.x * blockDim.x + threadIdx.x;
    if (i >= n) return;
    float b0 = b[0], b1 = b[1], b2 = b[2], b3 = b[3];
    float v0 = agg[i * 4 + 0] + b0;
    float v1 = agg[i * 4 + 1] + b1;
    float v2 = agg[i * 4 + 2] + b2;
    float v3 = agg[i * 4 + 3] + b3;
    float m = fmaxf(fmaxf(v0, v1), fmaxf(v2, v3));
    float e0 = expf(v0 - m), e1 = expf(v1 - m), e2 = expf(v2 - m), e3 = expf(v3 - m);
    float inv = 1.f / (e0 + e1 + e2 + e3);
    out[i * 4 + 0] = e0 * inv;
    out[i * 4 + 1] = e1 * inv;
    out[i * 4 + 2] = e2 * inv;
    out[i * 4 + 3] = e3 * inv;
}

static inline int cdiv(long long a, int b) { return (int)((a + b - 1) / b); }

extern "C" void kernel_launch(void* const* d_in, const int* in_sizes, int n_in,
                              void* d_out, int out_size, void* d_ws, size_t ws_size,
                              hipStream_t stream) {
    const float* x   = (const float*)d_in[0];
    const int*   ei  = (const int*)d_in[1];
    const float* ew  = (const float*)d_in[2];
    const float* W1  = (const float*)d_in[3];
    const float* b1  = (const float*)d_in[4];
    const float* W2  = (const float*)d_in[5];
    const float* b2  = (const float*)d_in[6];
    const float* W3  = (const float*)d_in[7];
    const float* b3  = (const float*)d_in[8];
    float* out = (float*)d_out;

    const int N = in_sizes[0] / 128;
    const int E = in_sizes[2];
    const int* src = ei;
    const int* dst = ei + E;

    float* dis  = (float*)d_ws;          // N
    float* bufA = dis + N;               // N*64
    float* bufB = bufA + (size_t)N * 64; // N*64

    // --- normalization ---
    k_init_deg<<<cdiv(N, BLK), BLK, 0, stream>>>(dis, N);
    k_deg_edges<<<cdiv(E, BLK), BLK, 0, stream>>>(dst, ew, dis, E);
    k_finish_dis<<<cdiv(N, BLK), BLK, 0, stream>>>(dis, N);

    // --- layer 1: x[N,128] -> h1[N,64] ---
    k_linear<128, 64, false><<<cdiv(N, 64), 256, 0, stream>>>(x, W1, nullptr, bufA, N);
    k_selfloop<64><<<cdiv((long long)N * 64, BLK), BLK, 0, stream>>>(bufA, dis, bufB, N);
    k_scatter<64><<<cdiv((long long)E * 64, BLK), BLK, 0, stream>>>(src, dst, ew, dis, bufA, bufB, E);

    // --- layer 2: leaky(agg1+b1)[N,64] -> h2[N,32] ---
    k_linear<64, 32, true><<<cdiv(N, 64), 256, 0, stream>>>(bufB, W2, b1, bufA, N);
    k_selfloop<32><<<cdiv((long long)N * 32, BLK), BLK, 0, stream>>>(bufA, dis, bufB, N);
    k_scatter<32><<<cdiv((long long)E * 32, BLK), BLK, 0, stream>>>(src, dst, ew, dis, bufA, bufB, E);

    // --- layer 3: leaky(agg2+b2)[N,32] -> h3[N,4] ---
    k_linear<32, 4, true><<<cdiv(N, 64), 256, 0, stream>>>(bufB, W3, b2, bufA, N);
    k_selfloop<4><<<cdiv((long long)N * 4, BLK), BLK, 0, stream>>>(bufA, dis, bufB, N);
    k_scatter<4><<<cdiv((long long)E * 4, BLK), BLK, 0, stream>>>(src, dst, ew, dis, bufA, bufB, E);

    k_softmax4<<<cdiv(N, BLK), BLK, 0, stream>>>(bufB, b3, out, N);
}

// Round 8
// 1012.765 us; speedup vs baseline: 3.3600x; 1.4450x over previous
//
#include <hip/hip_runtime.h>
#include <hip/hip_bf16.h>

// GCN 3-layer forward: x[N,128] -> GCNConv(64) -> leaky -> GCNConv(32) -> leaky
// -> GCNConv(4) -> softmax.  N=100000, E=3200000.
// Round 8: round-7 profile showed k_scatter<64> = 662us, WRITE_SIZE 800 MB =
// every f32 atomicAdd writing through to the memory side (random dst across
// 8 XCDs -> no L2 coalescing). Replace atomic scatter with an on-device CSR
// (built once, reused by all 3 layers) + per-node register-accumulated gather
// (self-loop fused, agg written exactly once).

#define BLK 256

__global__ void k_init_deg(float* __restrict__ deg, int n) {
    int i = blockIdx.x * blockDim.x + threadIdx.x;
    if (i < n) deg[i] = 1.0f;   // self-loop weight
}

// cnt[d] += 1 (edges per dst), deg[d] += w  (both L2-resident, N*4 B)
__global__ void k_count(const int* __restrict__ dst, const float* __restrict__ w,
                        int* __restrict__ cnt, float* __restrict__ deg, int E) {
    int e = blockIdx.x * blockDim.x + threadIdx.x;
    if (e < E) {
        int d = dst[e];
        atomicAdd(&cnt[d], 1);
        atomicAdd(&deg[d], w[e]);
    }
}

__global__ void k_finish_dis(float* __restrict__ deg, int n) {
    int i = blockIdx.x * blockDim.x + threadIdx.x;
    if (i < n) {
        float d = deg[i];
        deg[i] = d > 0.f ? rsqrtf(d) : 0.f;
    }
}

// ---- 3-kernel exclusive scan of cnt[0..n) into row_ptr (n <= 512*256) ----
__global__ void k_scan1(const int* __restrict__ cnt, int* __restrict__ row_ptr,
                        int* __restrict__ partials, int n) {
    __shared__ int sm[256];
    int i = blockIdx.x * 256 + threadIdx.x;
    int v = (i < n) ? cnt[i] : 0;
    sm[threadIdx.x] = v;
    __syncthreads();
    for (int off = 1; off < 256; off <<= 1) {
        int t = (threadIdx.x >= off) ? sm[threadIdx.x - off] : 0;
        __syncthreads();
        sm[threadIdx.x] += t;
        __syncthreads();
    }
    if (i < n) row_ptr[i] = sm[threadIdx.x] - v;      // block-local exclusive
    if (threadIdx.x == 255) partials[blockIdx.x] = sm[255];
}

__global__ void k_scan2(int* __restrict__ partials, int nb) {
    __shared__ int sm[512];
    int t = threadIdx.x;
    int v = (t < nb) ? partials[t] : 0;
    sm[t] = v;
    __syncthreads();
    for (int off = 1; off < 512; off <<= 1) {
        int x = (t >= off) ? sm[t - off] : 0;
        __syncthreads();
        sm[t] += x;
        __syncthreads();
    }
    if (t < nb) partials[t] = sm[t] - v;              // exclusive
}

__global__ void k_scan3(int* __restrict__ row_ptr, const int* __restrict__ partials,
                        int n, int E) {
    int i = blockIdx.x * 256 + threadIdx.x;
    if (i < n) row_ptr[i] += partials[i >> 8];
    else if (i == n) row_ptr[n] = E;
}

// bucket edges by dst: pack[pos] = (src, norm) with norm = dis[s]*w*dis[d]
__global__ void k_fill(const int* __restrict__ src, const int* __restrict__ dst,
                       const float* __restrict__ w, const float* __restrict__ dis,
                       const int* __restrict__ row_ptr, int* __restrict__ fill,
                       int2* __restrict__ pack, int E) {
    int e = blockIdx.x * blockDim.x + threadIdx.x;
    if (e >= E) return;
    int s = src[e], d = dst[e];
    float nm = dis[s] * w[e] * dis[d];
    int slot = atomicAdd(&fill[d], 1);
    pack[row_ptr[d] + slot] = make_int2(s, __float_as_int(nm));
}

__device__ __forceinline__ float leaky01(float v) {
    return v > 0.f ? v : 0.01f * v;
}

// Tiled linear: out[n][c] = sum_k act(in[n][k]) * W[c][k], act = leaky(x + bias_in).
template<int FIN, int FOUT, bool ACT>
__global__ __launch_bounds__(256) void k_linear(
        const float* __restrict__ in, const float* __restrict__ W,
        const float* __restrict__ bias_in, float* __restrict__ out, int n) {
    constexpr int TM = 64;            // nodes per block
    constexpr int CPT = FOUT / 4;     // columns per thread (16 / 8 / 1)
    __shared__ __align__(16) float Wt[FIN * FOUT];   // Wt[k*FOUT + c]
    __shared__ __align__(16) float xst[TM * FIN];    // xst[k*TM + node]

    const int tid = threadIdx.x;
    const int nb = blockIdx.x * TM;

    for (int i = tid; i < FIN * FOUT; i += 256) {
        int c = i / FIN, k = i % FIN;
        Wt[k * FOUT + c] = W[i];
    }
    __syncthreads();

    for (int i4 = tid; i4 < TM * FIN / 4; i4 += 256) {
        int idx = i4 * 4;
        int r = idx / FIN, k0 = idx % FIN;
        if (nb + r < n) {
            float4 v = *(const float4*)&in[(size_t)(nb + r) * FIN + k0];
            if (ACT) {
                float4 b = *(const float4*)&bias_in[k0];
                v.x = leaky01(v.x + b.x); v.y = leaky01(v.y + b.y);
                v.z = leaky01(v.z + b.z); v.w = leaky01(v.w + b.w);
            }
            xst[(k0 + 0) * TM + r] = v.x;
            xst[(k0 + 1) * TM + r] = v.y;
            xst[(k0 + 2) * TM + r] = v.z;
            xst[(k0 + 3) * TM + r] = v.w;
        }
    }
    __syncthreads();

    const int nl = tid >> 2;
    const int c0 = (tid & 3) * CPT;
    if (nb + nl >= n) return;

    if constexpr (CPT >= 4) {
        float4 acc[CPT / 4];
#pragma unroll
        for (int j = 0; j < CPT / 4; ++j) acc[j] = make_float4(0.f, 0.f, 0.f, 0.f);
#pragma unroll 8
        for (int k = 0; k < FIN; ++k) {
            float xv = xst[k * TM + nl];
            const float4* wr = (const float4*)&Wt[k * FOUT + c0];
#pragma unroll
            for (int j = 0; j < CPT / 4; ++j) {
                float4 w4 = wr[j];
                acc[j].x += xv * w4.x; acc[j].y += xv * w4.y;
                acc[j].z += xv * w4.z; acc[j].w += xv * w4.w;
            }
        }
        float4* o = (float4*)&out[(size_t)(nb + nl) * FOUT + c0];
#pragma unroll
        for (int j = 0; j < CPT / 4; ++j) o[j] = acc[j];
    } else {  // CPT == 1 (FOUT == 4)
        float acc = 0.f;
#pragma unroll 8
        for (int k = 0; k < FIN; ++k)
            acc += xst[k * TM + nl] * Wt[k * FOUT + c0];
        out[(size_t)(nb + nl) * FOUT + c0] = acc;
    }
}

// CSR gather: one F-lane group per dst node. acc = dis[d]^2*h[d][c] (self-loop)
//             + sum_j norm_j * h[src_j][c].  agg written exactly once, no atomics.
template<int F>
__global__ __launch_bounds__(256) void k_gather(
        const int* __restrict__ rp, const int2* __restrict__ pack,
        const float* __restrict__ dis, const float* __restrict__ h,
        float* __restrict__ agg, int n) {
    int node = blockIdx.x * (256 / F) + threadIdx.x / F;
    int c = threadIdx.x & (F - 1);
    if (node >= n) return;
    float dd = dis[node];
    float acc = dd * dd * h[(size_t)node * F + c];
    int beg = rp[node], end = rp[node + 1];
    for (int j = beg; j < end; ++j) {
        int2 p = pack[j];                              // broadcast within group
        acc += __int_as_float(p.y) * h[(size_t)p.x * F + c];  // coalesced gather
    }
    agg[(size_t)node * F + c] = acc;
}

__global__ void k_softmax4(const float* __restrict__ agg, const float* __restrict__ b,
                           float* __restrict__ out, int n) {
    int i = blockIdx.x * blockDim.x + threadIdx.x;
    if (i >= n) return;
    float b0 = b[0], b1 = b[1], b2 = b[2], b3 = b[3];
    float v0 = agg[i * 4 + 0] + b0;
    float v1 = agg[i * 4 + 1] + b1;
    float v2 = agg[i * 4 + 2] + b2;
    float v3 = agg[i * 4 + 3] + b3;
    float m = fmaxf(fmaxf(v0, v1), fmaxf(v2, v3));
    float e0 = expf(v0 - m), e1 = expf(v1 - m), e2 = expf(v2 - m), e3 = expf(v3 - m);
    float inv = 1.f / (e0 + e1 + e2 + e3);
    out[i * 4 + 0] = e0 * inv;
    out[i * 4 + 1] = e1 * inv;
    out[i * 4 + 2] = e2 * inv;
    out[i * 4 + 3] = e3 * inv;
}

static inline int cdiv(long long a, int b) { return (int)((a + b - 1) / b); }

extern "C" void kernel_launch(void* const* d_in, const int* in_sizes, int n_in,
                              void* d_out, int out_size, void* d_ws, size_t ws_size,
                              hipStream_t stream) {
    const float* x   = (const float*)d_in[0];
    const int*   ei  = (const int*)d_in[1];
    const float* ew  = (const float*)d_in[2];
    const float* W1  = (const float*)d_in[3];
    const float* b1  = (const float*)d_in[4];
    const float* W2  = (const float*)d_in[5];
    const float* b2  = (const float*)d_in[6];
    const float* W3  = (const float*)d_in[7];
    const float* b3  = (const float*)d_in[8];
    float* out = (float*)d_out;

    const int N = in_sizes[0] / 128;
    const int E = in_sizes[2];
    const int* src = ei;
    const int* dst = ei + E;

    // workspace carve (256-B aligned regions)
    char* base = (char*)d_ws;
    auto alloc = [&](size_t bytes) {
        char* p = base;
        base += (bytes + 255) & ~(size_t)255;
        return p;
    };
    float* dis      = (float*)alloc((size_t)N * 4);
    int*   cnt      = (int*)  alloc((size_t)N * 4);       // reused as fill cursor
    int*   row_ptr  = (int*)  alloc(((size_t)N + 1) * 4);
    int*   partials = (int*)  alloc(512 * 4);
    int2*  pack     = (int2*) alloc((size_t)E * 8);
    float* bufA     = (float*)alloc((size_t)N * 64 * 4);
    float* bufB     = (float*)alloc((size_t)N * 64 * 4);

    const int nb = cdiv(N, 256);   // scan blocks (391 <= 512)

    // --- normalization + CSR build (once, reused by all 3 layers) ---
    hipMemsetAsync(cnt, 0, (size_t)N * 4, stream);
    k_init_deg<<<cdiv(N, BLK), BLK, 0, stream>>>(dis, N);
    k_count<<<cdiv(E, BLK), BLK, 0, stream>>>(dst, ew, cnt, dis, E);
    k_finish_dis<<<cdiv(N, BLK), BLK, 0, stream>>>(dis, N);
    k_scan1<<<nb, 256, 0, stream>>>(cnt, row_ptr, partials, N);
    k_scan2<<<1, 512, 0, stream>>>(partials, nb);
    k_scan3<<<cdiv((long long)N + 1, 256), 256, 0, stream>>>(row_ptr, partials, N, E);
    hipMemsetAsync(cnt, 0, (size_t)N * 4, stream);
    k_fill<<<cdiv(E, BLK), BLK, 0, stream>>>(src, dst, ew, dis, row_ptr, cnt, pack, E);

    // --- layer 1: x[N,128] -> h1[N,64] ---
    k_linear<128, 64, false><<<cdiv(N, 64), 256, 0, stream>>>(x, W1, nullptr, bufA, N);
    k_gather<64><<<cdiv(N, 4), 256, 0, stream>>>(row_ptr, pack, dis, bufA, bufB, N);

    // --- layer 2: leaky(agg1+b1)[N,64] -> h2[N,32] ---
    k_linear<64, 32, true><<<cdiv(N, 64), 256, 0, stream>>>(bufB, W2, b1, bufA, N);
    k_gather<32><<<cdiv(N, 8), 256, 0, stream>>>(row_ptr, pack, dis, bufA, bufB, N);

    // --- layer 3: leaky(agg2+b2)[N,32] -> h3[N,4] ---
    k_linear<32, 4, true><<<cdiv(N, 64), 256, 0, stream>>>(bufB, W3, b2, bufA, N);
    k_gather<4><<<cdiv(N, 64), 256, 0, stream>>>(row_ptr, pack, dis, bufA, bufB, N);

    k_softmax4<<<cdiv(N, BLK), BLK, 0, stream>>>(bufB, b3, out, N);
}

// Round 9
// 703.953 us; speedup vs baseline: 4.8339x; 1.4387x over previous
//
#include <hip/hip_runtime.h>
#include <hip/hip_bf16.h>

// GCN 3-layer forward: x[N,128] -> GCNConv(64) -> leaky -> GCNConv(32) -> leaky
// -> GCNConv(4) -> softmax.  N=100000, E=3200000.
// Round 9: (a) k_count drops the deg atomic (cnt only); deg/dis computed from the
// CSR by contiguous sweeps (k_dis, k_norm) -- round-8 showed k_count's 6.4M atomics
// write through at 32B/atomic = 200 MB, 277us. (b) gather loop unrolled x4 for MLP
// (round-8 gather was latency-bound: VALUBusy 16%, 1.46 TB/s).

#define BLK 256

// cnt[d] += 1 (edges per dst)
__global__ void k_count(const int* __restrict__ dst, int* __restrict__ cnt, int E) {
    int e = blockIdx.x * blockDim.x + threadIdx.x;
    if (e < E) atomicAdd(&cnt[dst[e]], 1);
}

// ---- 3-kernel exclusive scan of cnt[0..n) into row_ptr (n <= 512*256) ----
__global__ void k_scan1(const int* __restrict__ cnt, int* __restrict__ row_ptr,
                        int* __restrict__ partials, int n) {
    __shared__ int sm[256];
    int i = blockIdx.x * 256 + threadIdx.x;
    int v = (i < n) ? cnt[i] : 0;
    sm[threadIdx.x] = v;
    __syncthreads();
    for (int off = 1; off < 256; off <<= 1) {
        int t = (threadIdx.x >= off) ? sm[threadIdx.x - off] : 0;
        __syncthreads();
        sm[threadIdx.x] += t;
        __syncthreads();
    }
    if (i < n) row_ptr[i] = sm[threadIdx.x] - v;      // block-local exclusive
    if (threadIdx.x == 255) partials[blockIdx.x] = sm[255];
}

__global__ void k_scan2(int* __restrict__ partials, int nb) {
    __shared__ int sm[512];
    int t = threadIdx.x;
    int v = (t < nb) ? partials[t] : 0;
    sm[t] = v;
    __syncthreads();
    for (int off = 1; off < 512; off <<= 1) {
        int x = (t >= off) ? sm[t - off] : 0;
        __syncthreads();
        sm[t] += x;
        __syncthreads();
    }
    if (t < nb) partials[t] = sm[t] - v;              // exclusive
}

__global__ void k_scan3(int* __restrict__ row_ptr, const int* __restrict__ partials,
                        int n, int E) {
    int i = blockIdx.x * 256 + threadIdx.x;
    if (i < n) row_ptr[i] += partials[i >> 8];
    else if (i == n) row_ptr[n] = E;
}

// bucket edges by dst: pack[pos] = (src, w)  (norm filled later by k_norm)
__global__ void k_fill(const int* __restrict__ src, const int* __restrict__ dst,
                       const float* __restrict__ w, const int* __restrict__ row_ptr,
                       int* __restrict__ fill, int2* __restrict__ pack, int E) {
    int e = blockIdx.x * blockDim.x + threadIdx.x;
    if (e >= E) return;
    int s = src[e], d = dst[e];
    int slot = atomicAdd(&fill[d], 1);
    pack[row_ptr[d] + slot] = make_int2(s, __float_as_int(w[e]));
}

// one wave per node: dis[d] = rsqrt(1 + sum_j w_j)  (contiguous CSR sweep)
__global__ __launch_bounds__(256) void k_dis(const int* __restrict__ rp,
                                             const int2* __restrict__ pack,
                                             float* __restrict__ dis, int n) {
    int node = blockIdx.x * 4 + (threadIdx.x >> 6);
    int lane = threadIdx.x & 63;
    if (node >= n) return;
    int beg = rp[node], end = rp[node + 1];
    float s = 0.f;
    for (int j = beg + lane; j < end; j += 64)
        s += __int_as_float(pack[j].y);
#pragma unroll
    for (int off = 32; off >= 1; off >>= 1)
        s += __shfl_xor(s, off);
    if (lane == 0) dis[node] = rsqrtf(1.f + s);
}

// one wave per node: pack[j].y = dis[d] * w * dis[src]  (contiguous RMW)
__global__ __launch_bounds__(256) void k_norm(const int* __restrict__ rp,
                                              const float* __restrict__ dis,
                                              int2* __restrict__ pack, int n) {
    int node = blockIdx.x * 4 + (threadIdx.x >> 6);
    int lane = threadIdx.x & 63;
    if (node >= n) return;
    float dd = dis[node];
    int beg = rp[node], end = rp[node + 1];
    for (int j = beg + lane; j < end; j += 64) {
        int2 p = pack[j];
        p.y = __float_as_int(dd * __int_as_float(p.y) * dis[p.x]);
        pack[j] = p;
    }
}

__device__ __forceinline__ float leaky01(float v) {
    return v > 0.f ? v : 0.01f * v;
}

// Tiled linear: out[n][c] = sum_k act(in[n][k]) * W[c][k], act = leaky(x + bias_in).
template<int FIN, int FOUT, bool ACT>
__global__ __launch_bounds__(256) void k_linear(
        const float* __restrict__ in, const float* __restrict__ W,
        const float* __restrict__ bias_in, float* __restrict__ out, int n) {
    constexpr int TM = 64;            // nodes per block
    constexpr int CPT = FOUT / 4;     // columns per thread (16 / 8 / 1)
    __shared__ __align__(16) float Wt[FIN * FOUT];   // Wt[k*FOUT + c]
    __shared__ __align__(16) float xst[TM * FIN];    // xst[k*TM + node]

    const int tid = threadIdx.x;
    const int nb = blockIdx.x * TM;

    for (int i = tid; i < FIN * FOUT; i += 256) {
        int c = i / FIN, k = i % FIN;
        Wt[k * FOUT + c] = W[i];
    }
    __syncthreads();

    for (int i4 = tid; i4 < TM * FIN / 4; i4 += 256) {
        int idx = i4 * 4;
        int r = idx / FIN, k0 = idx % FIN;
        if (nb + r < n) {
            float4 v = *(const float4*)&in[(size_t)(nb + r) * FIN + k0];
            if (ACT) {
                float4 b = *(const float4*)&bias_in[k0];
                v.x = leaky01(v.x + b.x); v.y = leaky01(v.y + b.y);
                v.z = leaky01(v.z + b.z); v.w = leaky01(v.w + b.w);
            }
            xst[(k0 + 0) * TM + r] = v.x;
            xst[(k0 + 1) * TM + r] = v.y;
            xst[(k0 + 2) * TM + r] = v.z;
            xst[(k0 + 3) * TM + r] = v.w;
        }
    }
    __syncthreads();

    const int nl = tid >> 2;
    const int c0 = (tid & 3) * CPT;
    if (nb + nl >= n) return;

    if constexpr (CPT >= 4) {
        float4 acc[CPT / 4];
#pragma unroll
        for (int j = 0; j < CPT / 4; ++j) acc[j] = make_float4(0.f, 0.f, 0.f, 0.f);
#pragma unroll 8
        for (int k = 0; k < FIN; ++k) {
            float xv = xst[k * TM + nl];
            const float4* wr = (const float4*)&Wt[k * FOUT + c0];
#pragma unroll
            for (int j = 0; j < CPT / 4; ++j) {
                float4 w4 = wr[j];
                acc[j].x += xv * w4.x; acc[j].y += xv * w4.y;
                acc[j].z += xv * w4.z; acc[j].w += xv * w4.w;
            }
        }
        float4* o = (float4*)&out[(size_t)(nb + nl) * FOUT + c0];
#pragma unroll
        for (int j = 0; j < CPT / 4; ++j) o[j] = acc[j];
    } else {  // CPT == 1 (FOUT == 4)
        float acc = 0.f;
#pragma unroll 8
        for (int k = 0; k < FIN; ++k)
            acc += xst[k * TM + nl] * Wt[k * FOUT + c0];
        out[(size_t)(nb + nl) * FOUT + c0] = acc;
    }
}

// CSR gather, unrolled x4 for memory-level parallelism.
// acc = dis[d]^2*h[d][c] + sum_j norm_j * h[src_j][c]; agg written once, no atomics.
template<int F>
__global__ __launch_bounds__(256) void k_gather(
        const int* __restrict__ rp, const int2* __restrict__ pack,
        const float* __restrict__ dis, const float* __restrict__ h,
        float* __restrict__ agg, int n) {
    int node = blockIdx.x * (256 / F) + threadIdx.x / F;
    int c = threadIdx.x & (F - 1);
    if (node >= n) return;
    float dd = dis[node];
    float acc = dd * dd * h[(size_t)node * F + c];
    int beg = rp[node], end = rp[node + 1];
    int j = beg;
    for (; j + 4 <= end; j += 4) {
        int2 p0 = pack[j + 0];
        int2 p1 = pack[j + 1];
        int2 p2 = pack[j + 2];
        int2 p3 = pack[j + 3];
        float h0 = h[(size_t)p0.x * F + c];
        float h1 = h[(size_t)p1.x * F + c];
        float h2 = h[(size_t)p2.x * F + c];
        float h3 = h[(size_t)p3.x * F + c];
        acc += __int_as_float(p0.y) * h0;
        acc += __int_as_float(p1.y) * h1;
        acc += __int_as_float(p2.y) * h2;
        acc += __int_as_float(p3.y) * h3;
    }
    for (; j < end; ++j) {
        int2 p = pack[j];
        acc += __int_as_float(p.y) * h[(size_t)p.x * F + c];
    }
    agg[(size_t)node * F + c] = acc;
}

__global__ void k_softmax4(const float* __restrict__ agg, const float* __restrict__ b,
                           float* __restrict__ out, int n) {
    int i = blockIdx.x * blockDim.x + threadIdx.x;
    if (i >= n) return;
    float b0 = b[0], b1 = b[1], b2 = b[2], b3 = b[3];
    float v0 = agg[i * 4 + 0] + b0;
    float v1 = agg[i * 4 + 1] + b1;
    float v2 = agg[i * 4 + 2] + b2;
    float v3 = agg[i * 4 + 3] + b3;
    float m = fmaxf(fmaxf(v0, v1), fmaxf(v2, v3));
    float e0 = expf(v0 - m), e1 = expf(v1 - m), e2 = expf(v2 - m), e3 = expf(v3 - m);
    float inv = 1.f / (e0 + e1 + e2 + e3);
    out[i * 4 + 0] = e0 * inv;
    out[i * 4 + 1] = e1 * inv;
    out[i * 4 + 2] = e2 * inv;
    out[i * 4 + 3] = e3 * inv;
}

static inline int cdiv(long long a, int b) { return (int)((a + b - 1) / b); }

extern "C" void kernel_launch(void* const* d_in, const int* in_sizes, int n_in,
                              void* d_out, int out_size, void* d_ws, size_t ws_size,
                              hipStream_t stream) {
    const float* x   = (const float*)d_in[0];
    const int*   ei  = (const int*)d_in[1];
    const float* ew  = (const float*)d_in[2];
    const float* W1  = (const float*)d_in[3];
    const float* b1  = (const float*)d_in[4];
    const float* W2  = (const float*)d_in[5];
    const float* b2  = (const float*)d_in[6];
    const float* W3  = (const float*)d_in[7];
    const float* b3  = (const float*)d_in[8];
    float* out = (float*)d_out;

    const int N = in_sizes[0] / 128;
    const int E = in_sizes[2];
    const int* src = ei;
    const int* dst = ei + E;

    // workspace carve (256-B aligned regions)
    char* base = (char*)d_ws;
    auto alloc = [&](size_t bytes) {
        char* p = base;
        base += (bytes + 255) & ~(size_t)255;
        return p;
    };
    float* dis      = (float*)alloc((size_t)N * 4);
    int*   cnt      = (int*)  alloc((size_t)N * 4);       // reused as fill cursor
    int*   row_ptr  = (int*)  alloc(((size_t)N + 1) * 4);
    int*   partials = (int*)  alloc(512 * 4);
    int2*  pack     = (int2*) alloc((size_t)E * 8);
    float* bufA     = (float*)alloc((size_t)N * 64 * 4);
    float* bufB     = (float*)alloc((size_t)N * 64 * 4);

    const int nb = cdiv(N, 256);   // scan blocks (391 <= 512)

    // --- CSR build + normalization (once, reused by all 3 layers) ---
    hipMemsetAsync(cnt, 0, (size_t)N * 4, stream);
    k_count<<<cdiv(E, BLK), BLK, 0, stream>>>(dst, cnt, E);
    k_scan1<<<nb, 256, 0, stream>>>(cnt, row_ptr, partials, N);
    k_scan2<<<1, 512, 0, stream>>>(partials, nb);
    k_scan3<<<cdiv((long long)N + 1, 256), 256, 0, stream>>>(row_ptr, partials, N, E);
    hipMemsetAsync(cnt, 0, (size_t)N * 4, stream);
    k_fill<<<cdiv(E, BLK), BLK, 0, stream>>>(src, dst, ew, row_ptr, cnt, pack, E);
    k_dis<<<cdiv(N, 4), 256, 0, stream>>>(row_ptr, pack, dis, N);
    k_norm<<<cdiv(N, 4), 256, 0, stream>>>(row_ptr, dis, pack, N);

    // --- layer 1: x[N,128] -> h1[N,64] ---
    k_linear<128, 64, false><<<cdiv(N, 64), 256, 0, stream>>>(x, W1, nullptr, bufA, N);
    k_gather<64><<<cdiv(N, 4), 256, 0, stream>>>(row_ptr, pack, dis, bufA, bufB, N);

    // --- layer 2: leaky(agg1+b1)[N,64] -> h2[N,32] ---
    k_linear<64, 32, true><<<cdiv(N, 64), 256, 0, stream>>>(bufB, W2, b1, bufA, N);
    k_gather<32><<<cdiv(N, 8), 256, 0, stream>>>(row_ptr, pack, dis, bufA, bufB, N);

    // --- layer 3: leaky(agg2+b2)[N,32] -> h3[N,4] ---
    k_linear<32, 4, true><<<cdiv(N, 64), 256, 0, stream>>>(bufB, W3, b2, bufA, N);
    k_gather<4><<<cdiv(N, 64), 256, 0, stream>>>(row_ptr, pack, dis, bufA, bufB, N);

    k_softmax4<<<cdiv(N, BLK), BLK, 0, stream>>>(bufB, b3, out, N);
}

// Round 10
// 469.042 us; speedup vs baseline: 7.2549x; 1.5008x over previous
//
#include <hip/hip_runtime.h>
#include <hip/hip_bf16.h>

// GCN 3-layer forward: x[N,128] -> GCNConv(64) -> leaky -> GCNConv(32) -> leaky
// -> GCNConv(4) -> softmax.  N=100000, E=3200000.
// Round 10: CSR build rewritten as a two-phase bucket sort (k_hist -> scan ->
// k_bscatter -> k_bcsr). Round-9 showed k_fill 210us / WRITE 200MB and k_count
// ~140us / WRITE 100MB: random 8B writes & atomics write through the 8
// non-coherent L2s at ~64B/line. Bucketing makes every random write land in a
// 130KB L2-resident window; cross-window writes are contiguous runs.

#define BLK 256

// ---- Phase A: per-block LDS histogram over dst buckets (bucket = dst>>9) ----
__global__ __launch_bounds__(256) void k_hist(const int* __restrict__ dst,
                                              int* __restrict__ hist,
                                              int E, int CH, int NB) {
    __shared__ int h[256];
    int b = blockIdx.x, t = threadIdx.x;
    h[t] = 0;
    __syncthreads();
    int beg = b * CH, fin = min(E, beg + CH);
    for (int e = beg + t; e < fin; e += 256)
        atomicAdd(&h[dst[e] >> 9], 1);
    __syncthreads();
    if (t < NB) hist[t * 256 + b] = h[t];   // bucket-major layout
}

// ---- 3-kernel exclusive scan (n <= 512*256) ----
__global__ void k_scan1(const int* __restrict__ in, int* __restrict__ outv,
                        int* __restrict__ partials, int n) {
    __shared__ int sm[256];
    int i = blockIdx.x * 256 + threadIdx.x;
    int v = (i < n) ? in[i] : 0;
    sm[threadIdx.x] = v;
    __syncthreads();
    for (int off = 1; off < 256; off <<= 1) {
        int t = (threadIdx.x >= off) ? sm[threadIdx.x - off] : 0;
        __syncthreads();
        sm[threadIdx.x] += t;
        __syncthreads();
    }
    if (i < n) outv[i] = sm[threadIdx.x] - v;        // block-local exclusive
    if (threadIdx.x == 255) partials[blockIdx.x] = sm[255];
}

__global__ void k_scan2(int* __restrict__ partials, int nb) {
    __shared__ int sm[512];
    int t = threadIdx.x;
    int v = (t < nb) ? partials[t] : 0;
    sm[t] = v;
    __syncthreads();
    for (int off = 1; off < 512; off <<= 1) {
        int x = (t >= off) ? sm[t - off] : 0;
        __syncthreads();
        sm[t] += x;
        __syncthreads();
    }
    if (t < nb) partials[t] = sm[t] - v;             // exclusive
}

__global__ void k_scan3(int* __restrict__ data, const int* __restrict__ partials, int n) {
    int i = blockIdx.x * 256 + threadIdx.x;
    if (i < n) data[i] += partials[i >> 8];
}

// ---- Phase C: scatter edges into bucket-sorted tmp (coalesced runs) ----
// record: x = (dlocal<<18) | src  (src < 2^18), y = w bits
__global__ __launch_bounds__(256) void k_bscatter(const int* __restrict__ src,
                                                  const int* __restrict__ dst,
                                                  const float* __restrict__ w,
                                                  const int* __restrict__ scanout,
                                                  int2* __restrict__ tmp,
                                                  int E, int CH, int NB) {
    __shared__ int cur[256];
    int b = blockIdx.x, t = threadIdx.x;
    if (t < NB) cur[t] = scanout[t * 256 + b];
    __syncthreads();
    int beg = b * CH, fin = min(E, beg + CH);
    for (int e = beg + t; e < fin; e += 256) {
        int d = dst[e];
        int q = d >> 9;
        int pos = atomicAdd(&cur[q], 1);             // LDS atomic
        tmp[pos] = make_int2(((d & 511) << 18) | src[e], __float_as_int(w[e]));
    }
}

// ---- Phase D: per-bucket CSR (one block per bucket; all random work L2-local) ----
__global__ __launch_bounds__(256) void k_bcsr(const int* __restrict__ scanout,
                                              const int2* __restrict__ tmp,
                                              int2* __restrict__ pack,
                                              int* __restrict__ row_ptr,
                                              int n, int E, int NB) {
    __shared__ int cnt[512];
    __shared__ int psum[256];
    int q = blockIdx.x, t = threadIdx.x;
    int base = scanout[q * 256];
    int end  = (q == NB - 1) ? E : scanout[(q + 1) * 256];
    cnt[t] = 0; cnt[t + 256] = 0;
    __syncthreads();
    for (int j = base + t; j < end; j += 256)
        atomicAdd(&cnt[tmp[j].x >> 18], 1);
    __syncthreads();
    // exclusive scan of cnt[512] with 256 threads (pairwise + Hillis-Steele)
    int a = cnt[2 * t], bb = cnt[2 * t + 1];
    psum[t] = a + bb;
    __syncthreads();
    for (int off = 1; off < 256; off <<= 1) {
        int v = (t >= off) ? psum[t - off] : 0;
        __syncthreads();
        psum[t] += v;
        __syncthreads();
    }
    int pex = psum[t] - (a + bb);                    // exclusive pair prefix
    __syncthreads();
    cnt[2 * t] = pex;                                // becomes fill cursor
    cnt[2 * t + 1] = pex + a;
    int node0 = q * 512;
    if (node0 + 2 * t < n)     row_ptr[node0 + 2 * t]     = base + pex;
    if (node0 + 2 * t + 1 < n) row_ptr[node0 + 2 * t + 1] = base + pex + a;
    if (q == 0 && t == 0) row_ptr[n] = E;
    __syncthreads();
    for (int j = base + t; j < end; j += 256) {
        int2 r = tmp[j];
        int d = r.x >> 18;
        int pos = base + atomicAdd(&cnt[d], 1);      // LDS atomic
        pack[pos] = make_int2(r.x & 0x3FFFF, r.y);
    }
}

// one wave per node: dis[d] = rsqrt(1 + sum_j w_j)  (contiguous CSR sweep)
__global__ __launch_bounds__(256) void k_dis(const int* __restrict__ rp,
                                             const int2* __restrict__ pack,
                                             float* __restrict__ dis, int n) {
    int node = blockIdx.x * 4 + (threadIdx.x >> 6);
    int lane = threadIdx.x & 63;
    if (node >= n) return;
    int beg = rp[node], end = rp[node + 1];
    float s = 0.f;
    for (int j = beg + lane; j < end; j += 64)
        s += __int_as_float(pack[j].y);
#pragma unroll
    for (int off = 32; off >= 1; off >>= 1)
        s += __shfl_xor(s, off);
    if (lane == 0) dis[node] = rsqrtf(1.f + s);
}

// one wave per node: pack[j].y = dis[d] * w * dis[src]  (contiguous RMW)
__global__ __launch_bounds__(256) void k_norm(const int* __restrict__ rp,
                                              const float* __restrict__ dis,
                                              int2* __restrict__ pack, int n) {
    int node = blockIdx.x * 4 + (threadIdx.x >> 6);
    int lane = threadIdx.x & 63;
    if (node >= n) return;
    float dd = dis[node];
    int beg = rp[node], end = rp[node + 1];
    for (int j = beg + lane; j < end; j += 64) {
        int2 p = pack[j];
        p.y = __float_as_int(dd * __int_as_float(p.y) * dis[p.x]);
        pack[j] = p;
    }
}

__device__ __forceinline__ float leaky01(float v) {
    return v > 0.f ? v : 0.01f * v;
}

// Tiled linear: out[n][c] = sum_k act(in[n][k]) * W[c][k], act = leaky(x + bias_in).
template<int FIN, int FOUT, bool ACT>
__global__ __launch_bounds__(256) void k_linear(
        const float* __restrict__ in, const float* __restrict__ W,
        const float* __restrict__ bias_in, float* __restrict__ out, int n) {
    constexpr int TM = 64;
    constexpr int CPT = FOUT / 4;
    __shared__ __align__(16) float Wt[FIN * FOUT];
    __shared__ __align__(16) float xst[TM * FIN];

    const int tid = threadIdx.x;
    const int nb = blockIdx.x * TM;

    for (int i = tid; i < FIN * FOUT; i += 256) {
        int c = i / FIN, k = i % FIN;
        Wt[k * FOUT + c] = W[i];
    }
    __syncthreads();

    for (int i4 = tid; i4 < TM * FIN / 4; i4 += 256) {
        int idx = i4 * 4;
        int r = idx / FIN, k0 = idx % FIN;
        if (nb + r < n) {
            float4 v = *(const float4*)&in[(size_t)(nb + r) * FIN + k0];
            if (ACT) {
                float4 b = *(const float4*)&bias_in[k0];
                v.x = leaky01(v.x + b.x); v.y = leaky01(v.y + b.y);
                v.z = leaky01(v.z + b.z); v.w = leaky01(v.w + b.w);
            }
            xst[(k0 + 0) * TM + r] = v.x;
            xst[(k0 + 1) * TM + r] = v.y;
            xst[(k0 + 2) * TM + r] = v.z;
            xst[(k0 + 3) * TM + r] = v.w;
        }
    }
    __syncthreads();

    const int nl = tid >> 2;
    const int c0 = (tid & 3) * CPT;
    if (nb + nl >= n) return;

    if constexpr (CPT >= 4) {
        float4 acc[CPT / 4];
#pragma unroll
        for (int j = 0; j < CPT / 4; ++j) acc[j] = make_float4(0.f, 0.f, 0.f, 0.f);
#pragma unroll 8
        for (int k = 0; k < FIN; ++k) {
            float xv = xst[k * TM + nl];
            const float4* wr = (const float4*)&Wt[k * FOUT + c0];
#pragma unroll
            for (int j = 0; j < CPT / 4; ++j) {
                float4 w4 = wr[j];
                acc[j].x += xv * w4.x; acc[j].y += xv * w4.y;
                acc[j].z += xv * w4.z; acc[j].w += xv * w4.w;
            }
        }
        float4* o = (float4*)&out[(size_t)(nb + nl) * FOUT + c0];
#pragma unroll
        for (int j = 0; j < CPT / 4; ++j) o[j] = acc[j];
    } else {  // CPT == 1 (FOUT == 4)
        float acc = 0.f;
#pragma unroll 8
        for (int k = 0; k < FIN; ++k)
            acc += xst[k * TM + nl] * Wt[k * FOUT + c0];
        out[(size_t)(nb + nl) * FOUT + c0] = acc;
    }
}

// CSR gather, unrolled x4 for memory-level parallelism.
template<int F>
__global__ __launch_bounds__(256) void k_gather(
        const int* __restrict__ rp, const int2* __restrict__ pack,
        const float* __restrict__ dis, const float* __restrict__ h,
        float* __restrict__ agg, int n) {
    int node = blockIdx.x * (256 / F) + threadIdx.x / F;
    int c = threadIdx.x & (F - 1);
    if (node >= n) return;
    float dd = dis[node];
    float acc = dd * dd * h[(size_t)node * F + c];
    int beg = rp[node], end = rp[node + 1];
    int j = beg;
    for (; j + 4 <= end; j += 4) {
        int2 p0 = pack[j + 0];
        int2 p1 = pack[j + 1];
        int2 p2 = pack[j + 2];
        int2 p3 = pack[j + 3];
        float h0 = h[(size_t)p0.x * F + c];
        float h1 = h[(size_t)p1.x * F + c];
        float h2 = h[(size_t)p2.x * F + c];
        float h3 = h[(size_t)p3.x * F + c];
        acc += __int_as_float(p0.y) * h0;
        acc += __int_as_float(p1.y) * h1;
        acc += __int_as_float(p2.y) * h2;
        acc += __int_as_float(p3.y) * h3;
    }
    for (; j < end; ++j) {
        int2 p = pack[j];
        acc += __int_as_float(p.y) * h[(size_t)p.x * F + c];
    }
    agg[(size_t)node * F + c] = acc;
}

__global__ void k_softmax4(const float* __restrict__ agg, const float* __restrict__ b,
                           float* __restrict__ out, int n) {
    int i = blockIdx.x * blockDim.x + threadIdx.x;
    if (i >= n) return;
    float b0 = b[0], b1 = b[1], b2 = b[2], b3 = b[3];
    float v0 = agg[i * 4 + 0] + b0;
    float v1 = agg[i * 4 + 1] + b1;
    float v2 = agg[i * 4 + 2] + b2;
    float v3 = agg[i * 4 + 3] + b3;
    float m = fmaxf(fmaxf(v0, v1), fmaxf(v2, v3));
    float e0 = expf(v0 - m), e1 = expf(v1 - m), e2 = expf(v2 - m), e3 = expf(v3 - m);
    float inv = 1.f / (e0 + e1 + e2 + e3);
    out[i * 4 + 0] = e0 * inv;
    out[i * 4 + 1] = e1 * inv;
    out[i * 4 + 2] = e2 * inv;
    out[i * 4 + 3] = e3 * inv;
}

static inline int cdiv(long long a, int b) { return (int)((a + b - 1) / b); }

extern "C" void kernel_launch(void* const* d_in, const int* in_sizes, int n_in,
                              void* d_out, int out_size, void* d_ws, size_t ws_size,
                              hipStream_t stream) {
    const float* x   = (const float*)d_in[0];
    const int*   ei  = (const int*)d_in[1];
    const float* ew  = (const float*)d_in[2];
    const float* W1  = (const float*)d_in[3];
    const float* b1  = (const float*)d_in[4];
    const float* W2  = (const float*)d_in[5];
    const float* b2  = (const float*)d_in[6];
    const float* W3  = (const float*)d_in[7];
    const float* b3  = (const float*)d_in[8];
    float* out = (float*)d_out;

    const int N = in_sizes[0] / 128;
    const int E = in_sizes[2];
    const int* src = ei;
    const int* dst = ei + E;

    const int NB = (N + 511) >> 9;          // 196 buckets of 512 nodes
    const int GB = 256;                     // hist/scatter blocks
    const int CH = cdiv(E, GB);             // edges per block chunk
    const int n_scan = NB * GB;             // 50176

    // workspace carve (256-B aligned regions)
    char* base = (char*)d_ws;
    auto alloc = [&](size_t bytes) {
        char* p = base;
        base += (bytes + 255) & ~(size_t)255;
        return p;
    };
    float* dis      = (float*)alloc((size_t)N * 4);
    int*   row_ptr  = (int*)  alloc(((size_t)N + 1) * 4);
    int*   hist     = (int*)  alloc((size_t)n_scan * 4);
    int*   scanout  = (int*)  alloc((size_t)n_scan * 4);
    int*   partials = (int*)  alloc(512 * 4);
    int2*  pack     = (int2*) alloc((size_t)E * 8);
    float* bufA     = (float*)alloc((size_t)N * 64 * 4);
    float* bufB     = (float*)alloc((size_t)N * 64 * 4);
    int2*  tmp      = (int2*)bufA;          // aliases bufA (free until linear-1)

    // --- CSR build via bucket sort (once, reused by all 3 layers) ---
    k_hist<<<GB, 256, 0, stream>>>(dst, hist, E, CH, NB);
    k_scan1<<<cdiv(n_scan, 256), 256, 0, stream>>>(hist, scanout, partials, n_scan);
    k_scan2<<<1, 512, 0, stream>>>(partials, cdiv(n_scan, 256));
    k_scan3<<<cdiv(n_scan, 256), 256, 0, stream>>>(scanout, partials, n_scan);
    k_bscatter<<<GB, 256, 0, stream>>>(src, dst, ew, scanout, tmp, E, CH, NB);
    k_bcsr<<<NB, 256, 0, stream>>>(scanout, tmp, pack, row_ptr, N, E, NB);
    k_dis<<<cdiv(N, 4), 256, 0, stream>>>(row_ptr, pack, dis, N);
    k_norm<<<cdiv(N, 4), 256, 0, stream>>>(row_ptr, dis, pack, N);

    // --- layer 1: x[N,128] -> h1[N,64] ---
    k_linear<128, 64, false><<<cdiv(N, 64), 256, 0, stream>>>(x, W1, nullptr, bufA, N);
    k_gather<64><<<cdiv(N, 4), 256, 0, stream>>>(row_ptr, pack, dis, bufA, bufB, N);

    // --- layer 2: leaky(agg1+b1)[N,64] -> h2[N,32] ---
    k_linear<64, 32, true><<<cdiv(N, 64), 256, 0, stream>>>(bufB, W2, b1, bufA, N);
    k_gather<32><<<cdiv(N, 8), 256, 0, stream>>>(row_ptr, pack, dis, bufA, bufB, N);

    // --- layer 3: leaky(agg2+b2)[N,32] -> h3[N,4] ---
    k_linear<32, 4, true><<<cdiv(N, 64), 256, 0, stream>>>(bufB, W3, b2, bufA, N);
    k_gather<4><<<cdiv(N, 64), 256, 0, stream>>>(row_ptr, pack, dis, bufA, bufB, N);

    k_softmax4<<<cdiv(N, BLK), BLK, 0, stream>>>(bufB, b3, out, N);
}

// Round 11
// 449.664 us; speedup vs baseline: 7.5675x; 1.0431x over previous
//
#include <hip/hip_runtime.h>
#include <hip/hip_bf16.h>

// GCN 3-layer forward: x[N,128] -> GCNConv(64) -> leaky -> GCNConv(32) -> leaky
// -> GCNConv(4) -> softmax.  N=100000, E=3200000.
// Round 11: fusion round. (a) dis folded into k_bcsr (LDS wsum). (b) k_norm
// deleted -- gathers compute nm = dis[d]*w*dis[src] on the fly (broadcast
// L2-resident dis load per edge). (c) gather+act+next-linear fused:
// fgather64 -> h2 directly (W2 in LDS), fgather32 -> h3 (W3 in LDS),
// fgather4 -> softmax -> out. 15 dispatches -> 10, ~155 MB less traffic.

#define BLK 256

// ---- Phase A: per-block LDS histogram over dst buckets (bucket = dst>>9) ----
__global__ __launch_bounds__(256) void k_hist(const int* __restrict__ dst,
                                              int* __restrict__ hist,
                                              int E, int CH, int NB) {
    __shared__ int h[256];
    int b = blockIdx.x, t = threadIdx.x;
    h[t] = 0;
    __syncthreads();
    int beg = b * CH, fin = min(E, beg + CH);
    for (int e = beg + t; e < fin; e += 256)
        atomicAdd(&h[dst[e] >> 9], 1);
    __syncthreads();
    if (t < NB) hist[t * 256 + b] = h[t];   // bucket-major layout
}

// ---- 3-kernel exclusive scan (n <= 512*256) ----
__global__ void k_scan1(const int* __restrict__ in, int* __restrict__ outv,
                        int* __restrict__ partials, int n) {
    __shared__ int sm[256];
    int i = blockIdx.x * 256 + threadIdx.x;
    int v = (i < n) ? in[i] : 0;
    sm[threadIdx.x] = v;
    __syncthreads();
    for (int off = 1; off < 256; off <<= 1) {
        int t = (threadIdx.x >= off) ? sm[threadIdx.x - off] : 0;
        __syncthreads();
        sm[threadIdx.x] += t;
        __syncthreads();
    }
    if (i < n) outv[i] = sm[threadIdx.x] - v;
    if (threadIdx.x == 255) partials[blockIdx.x] = sm[255];
}

__global__ void k_scan2(int* __restrict__ partials, int nb) {
    __shared__ int sm[512];
    int t = threadIdx.x;
    int v = (t < nb) ? partials[t] : 0;
    sm[t] = v;
    __syncthreads();
    for (int off = 1; off < 512; off <<= 1) {
        int x = (t >= off) ? sm[t - off] : 0;
        __syncthreads();
        sm[t] += x;
        __syncthreads();
    }
    if (t < nb) partials[t] = sm[t] - v;
}

__global__ void k_scan3(int* __restrict__ data, const int* __restrict__ partials, int n) {
    int i = blockIdx.x * 256 + threadIdx.x;
    if (i < n) data[i] += partials[i >> 8];
}

// ---- Phase C: scatter edges into bucket-sorted tmp ----
// record: x = (dlocal<<18) | src  (src < 2^18), y = w bits
__global__ __launch_bounds__(256) void k_bscatter(const int* __restrict__ src,
                                                  const int* __restrict__ dst,
                                                  const float* __restrict__ w,
                                                  const int* __restrict__ scanout,
                                                  int2* __restrict__ tmp,
                                                  int E, int CH, int NB) {
    __shared__ int cur[256];
    int b = blockIdx.x, t = threadIdx.x;
    if (t < NB) cur[t] = scanout[t * 256 + b];
    __syncthreads();
    int beg = b * CH, fin = min(E, beg + CH);
    for (int e = beg + t; e < fin; e += 256) {
        int d = dst[e];
        int q = d >> 9;
        int pos = atomicAdd(&cur[q], 1);             // LDS atomic
        tmp[pos] = make_int2(((d & 511) << 18) | src[e], __float_as_int(w[e]));
    }
}

// ---- Phase D: per-bucket CSR + fused dis = rsqrt(1 + sum_w) ----
__global__ __launch_bounds__(256) void k_bcsr(const int* __restrict__ scanout,
                                              const int2* __restrict__ tmp,
                                              int2* __restrict__ pack,
                                              int* __restrict__ row_ptr,
                                              float* __restrict__ dis,
                                              int n, int E, int NB) {
    __shared__ int cnt[512];
    __shared__ float wsum[512];
    __shared__ int psum[256];
    int q = blockIdx.x, t = threadIdx.x;
    int base = scanout[q * 256];
    int end  = (q == NB - 1) ? E : scanout[(q + 1) * 256];
    cnt[t] = 0; cnt[t + 256] = 0;
    wsum[t] = 0.f; wsum[t + 256] = 0.f;
    __syncthreads();
    for (int j = base + t; j < end; j += 256) {
        int2 r = tmp[j];
        int d = r.x >> 18;
        atomicAdd(&cnt[d], 1);
        atomicAdd(&wsum[d], __int_as_float(r.y));
    }
    __syncthreads();
    // exclusive scan of cnt[512] with 256 threads
    int a = cnt[2 * t], bb = cnt[2 * t + 1];
    psum[t] = a + bb;
    __syncthreads();
    for (int off = 1; off < 256; off <<= 1) {
        int v = (t >= off) ? psum[t - off] : 0;
        __syncthreads();
        psum[t] += v;
        __syncthreads();
    }
    int pex = psum[t] - (a + bb);
    __syncthreads();
    cnt[2 * t] = pex;                                // fill cursors
    cnt[2 * t + 1] = pex + a;
    int node0 = q * 512;
    if (node0 + 2 * t < n) {
        row_ptr[node0 + 2 * t] = base + pex;
        dis[node0 + 2 * t] = rsqrtf(1.f + wsum[2 * t]);
    }
    if (node0 + 2 * t + 1 < n) {
        row_ptr[node0 + 2 * t + 1] = base + pex + a;
        dis[node0 + 2 * t + 1] = rsqrtf(1.f + wsum[2 * t + 1]);
    }
    if (q == 0 && t == 0) row_ptr[n] = E;
    __syncthreads();
    for (int j = base + t; j < end; j += 256) {
        int2 r = tmp[j];
        int d = r.x >> 18;
        int pos = base + atomicAdd(&cnt[d], 1);      // LDS atomic
        pack[pos] = make_int2(r.x & 0x3FFFF, r.y);   // (src, w)
    }
}

__device__ __forceinline__ float leaky01(float v) {
    return v > 0.f ? v : 0.01f * v;
}

// shared gather core: acc = dis^2*h[node][c] + sum_j dis[d]*w_j*dis[src_j]*h[src_j][c]
template<int F>
__device__ __forceinline__ float gather_acc(const int* __restrict__ rp,
                                            const int2* __restrict__ pack,
                                            const float* __restrict__ dis,
                                            const float* __restrict__ h,
                                            int node, int c, float dd) {
    float acc = dd * dd * h[(size_t)node * F + c];
    int beg = rp[node], end = rp[node + 1];
    int j = beg;
    for (; j + 4 <= end; j += 4) {
        int2 p0 = pack[j + 0];
        int2 p1 = pack[j + 1];
        int2 p2 = pack[j + 2];
        int2 p3 = pack[j + 3];
        float d0 = dis[p0.x], d1 = dis[p1.x], d2 = dis[p2.x], d3 = dis[p3.x];
        float h0 = h[(size_t)p0.x * F + c];
        float h1 = h[(size_t)p1.x * F + c];
        float h2 = h[(size_t)p2.x * F + c];
        float h3 = h[(size_t)p3.x * F + c];
        acc += dd * __int_as_float(p0.y) * d0 * h0;
        acc += dd * __int_as_float(p1.y) * d1 * h1;
        acc += dd * __int_as_float(p2.y) * d2 * h2;
        acc += dd * __int_as_float(p3.y) * d3 * h3;
    }
    for (; j < end; ++j) {
        int2 p = pack[j];
        acc += dd * __int_as_float(p.y) * dis[p.x] * h[(size_t)p.x * F + c];
    }
    return acc;
}

// layer-1 agg + leaky(+b1) + W2 matmul -> h2[N,32].  One 64-lane wave per node.
__global__ __launch_bounds__(256) void fgather64(
        const int* __restrict__ rp, const int2* __restrict__ pack,
        const float* __restrict__ dis, const float* __restrict__ h,   // h1 [n,64]
        const float* __restrict__ b1, const float* __restrict__ W2,   // [32][64]
        float* __restrict__ h2out, int n) {
    __shared__ float sW2t[64 * 33];    // [c][c2], padded
    __shared__ float sact[4][64];
    int tid = threadIdx.x;
    for (int i = tid; i < 2048; i += 256)
        sW2t[(i & 63) * 33 + (i >> 6)] = W2[i];
    int w = tid >> 6, l = tid & 63;
    int node = blockIdx.x * 4 + w;
    bool valid = node < n;
    float act = 0.f;
    if (valid) {
        float dd = dis[node];
        float acc = gather_acc<64>(rp, pack, dis, h, node, l, dd);
        act = leaky01(acc + b1[l]);
    }
    sact[w][l] = act;
    __syncthreads();
    if (valid) {
        int c2 = l & 31, half = l >> 5;
        float s = 0.f;
#pragma unroll 8
        for (int cc = 0; cc < 32; ++cc) {
            int c = half * 32 + cc;
            s += sW2t[c * 33 + c2] * sact[w][c];
        }
        s += __shfl_xor(s, 32);
        if (l < 32) h2out[(size_t)node * 32 + c2] = s;
    }
}

// layer-2 agg + leaky(+b2) + W3 matmul -> h3[N,4].  One 32-lane group per node.
__global__ __launch_bounds__(256) void fgather32(
        const int* __restrict__ rp, const int2* __restrict__ pack,
        const float* __restrict__ dis, const float* __restrict__ h,   // h2 [n,32]
        const float* __restrict__ b2, const float* __restrict__ W3,   // [4][32]
        float* __restrict__ h3out, int n) {
    __shared__ float sW3t[32 * 5];     // [c][c3], padded
    __shared__ float sact[8][32];
    int tid = threadIdx.x;
    if (tid < 128) sW3t[(tid & 31) * 5 + (tid >> 5)] = W3[tid];
    int w = tid >> 5, g = tid & 31;
    int node = blockIdx.x * 8 + w;
    bool valid = node < n;
    float act = 0.f;
    if (valid) {
        float dd = dis[node];
        float acc = gather_acc<32>(rp, pack, dis, h, node, g, dd);
        act = leaky01(acc + b2[g]);
    }
    sact[w][g] = act;
    __syncthreads();
    if (valid) {
        int c3 = g & 3;
        float s = 0.f;
#pragma unroll
        for (int m = 0; m < 4; ++m) {
            int c = (g >> 2) + 8 * m;
            s += sW3t[c * 5 + c3] * sact[w][c];
        }
        s += __shfl_xor(s, 4, 32);
        s += __shfl_xor(s, 8, 32);
        s += __shfl_xor(s, 16, 32);
        if (g < 4) h3out[(size_t)node * 4 + g] = s;
    }
}

// layer-3 agg + b3 + softmax -> out[N,4].  One 4-lane group per node.
__global__ __launch_bounds__(256) void fgather4(
        const int* __restrict__ rp, const int2* __restrict__ pack,
        const float* __restrict__ dis, const float* __restrict__ h,   // h3 [n,4]
        const float* __restrict__ b3, float* __restrict__ out, int n) {
    int tid = threadIdx.x;
    int node = blockIdx.x * 64 + (tid >> 2);
    int c = tid & 3;
    if (node >= n) return;
    float dd = dis[node];
    float acc = gather_acc<4>(rp, pack, dis, h, node, c, dd);
    float v = acc + b3[c];
    float m = fmaxf(v, __shfl_xor(v, 1, 4));
    m = fmaxf(m, __shfl_xor(m, 2, 4));
    float e = expf(v - m);
    float ssum = e + __shfl_xor(e, 1, 4);
    ssum += __shfl_xor(ssum, 2, 4);
    out[(size_t)node * 4 + c] = e / ssum;
}

// Tiled linear (layer 1 only): out[n][c] = sum_k in[n][k] * W[c][k].
template<int FIN, int FOUT, bool ACT>
__global__ __launch_bounds__(256) void k_linear(
        const float* __restrict__ in, const float* __restrict__ W,
        const float* __restrict__ bias_in, float* __restrict__ out, int n) {
    constexpr int TM = 64;
    constexpr int CPT = FOUT / 4;
    __shared__ __align__(16) float Wt[FIN * FOUT];
    __shared__ __align__(16) float xst[TM * FIN];

    const int tid = threadIdx.x;
    const int nb = blockIdx.x * TM;

    for (int i = tid; i < FIN * FOUT; i += 256) {
        int c = i / FIN, k = i % FIN;
        Wt[k * FOUT + c] = W[i];
    }
    __syncthreads();

    for (int i4 = tid; i4 < TM * FIN / 4; i4 += 256) {
        int idx = i4 * 4;
        int r = idx / FIN, k0 = idx % FIN;
        if (nb + r < n) {
            float4 v = *(const float4*)&in[(size_t)(nb + r) * FIN + k0];
            if (ACT) {
                float4 b = *(const float4*)&bias_in[k0];
                v.x = leaky01(v.x + b.x); v.y = leaky01(v.y + b.y);
                v.z = leaky01(v.z + b.z); v.w = leaky01(v.w + b.w);
            }
            xst[(k0 + 0) * TM + r] = v.x;
            xst[(k0 + 1) * TM + r] = v.y;
            xst[(k0 + 2) * TM + r] = v.z;
            xst[(k0 + 3) * TM + r] = v.w;
        }
    }
    __syncthreads();

    const int nl = tid >> 2;
    const int c0 = (tid & 3) * CPT;
    if (nb + nl >= n) return;

    float4 acc[CPT / 4];
#pragma unroll
    for (int j = 0; j < CPT / 4; ++j) acc[j] = make_float4(0.f, 0.f, 0.f, 0.f);
#pragma unroll 8
    for (int k = 0; k < FIN; ++k) {
        float xv = xst[k * TM + nl];
        const float4* wr = (const float4*)&Wt[k * FOUT + c0];
#pragma unroll
        for (int j = 0; j < CPT / 4; ++j) {
            float4 w4 = wr[j];
            acc[j].x += xv * w4.x; acc[j].y += xv * w4.y;
            acc[j].z += xv * w4.z; acc[j].w += xv * w4.w;
        }
    }
    float4* o = (float4*)&out[(size_t)(nb + nl) * FOUT + c0];
#pragma unroll
    for (int j = 0; j < CPT / 4; ++j) o[j] = acc[j];
}

static inline int cdiv(long long a, int b) { return (int)((a + b - 1) / b); }

extern "C" void kernel_launch(void* const* d_in, const int* in_sizes, int n_in,
                              void* d_out, int out_size, void* d_ws, size_t ws_size,
                              hipStream_t stream) {
    const float* x   = (const float*)d_in[0];
    const int*   ei  = (const int*)d_in[1];
    const float* ew  = (const float*)d_in[2];
    const float* W1  = (const float*)d_in[3];
    const float* b1  = (const float*)d_in[4];
    const float* W2  = (const float*)d_in[5];
    const float* b2  = (const float*)d_in[6];
    const float* W3  = (const float*)d_in[7];
    const float* b3  = (const float*)d_in[8];
    float* out = (float*)d_out;

    const int N = in_sizes[0] / 128;
    const int E = in_sizes[2];
    const int* src = ei;
    const int* dst = ei + E;

    const int NB = (N + 511) >> 9;          // buckets of 512 nodes
    const int GB = 256;
    const int CH = cdiv(E, GB);
    const int n_scan = NB * GB;

    char* base = (char*)d_ws;
    auto alloc = [&](size_t bytes) {
        char* p = base;
        base += (bytes + 255) & ~(size_t)255;
        return p;
    };
    float* dis      = (float*)alloc((size_t)N * 4);
    int*   row_ptr  = (int*)  alloc(((size_t)N + 1) * 4);
    int*   hist     = (int*)  alloc((size_t)n_scan * 4);
    int*   scanout  = (int*)  alloc((size_t)n_scan * 4);
    int*   partials = (int*)  alloc(512 * 4);
    int2*  pack     = (int2*) alloc((size_t)E * 8);
    float* bufA     = (float*)alloc((size_t)N * 64 * 4);
    float* bufB     = (float*)alloc((size_t)N * 64 * 4);
    int2*  tmp      = (int2*)bufA;          // aliases bufA (dead after k_bcsr)

    // --- CSR build via bucket sort; dis fused into k_bcsr ---
    k_hist<<<GB, 256, 0, stream>>>(dst, hist, E, CH, NB);
    k_scan1<<<cdiv(n_scan, 256), 256, 0, stream>>>(hist, scanout, partials, n_scan);
    k_scan2<<<1, 512, 0, stream>>>(partials, cdiv(n_scan, 256));
    k_scan3<<<cdiv(n_scan, 256), 256, 0, stream>>>(scanout, partials, n_scan);
    k_bscatter<<<GB, 256, 0, stream>>>(src, dst, ew, scanout, tmp, E, CH, NB);
    k_bcsr<<<NB, 256, 0, stream>>>(scanout, tmp, pack, row_ptr, dis, N, E, NB);

    // --- fused layers ---
    k_linear<128, 64, false><<<cdiv(N, 64), 256, 0, stream>>>(x, W1, nullptr, bufA, N);
    fgather64<<<cdiv(N, 4), 256, 0, stream>>>(row_ptr, pack, dis, bufA, b1, W2, bufB, N);
    fgather32<<<cdiv(N, 8), 256, 0, stream>>>(row_ptr, pack, dis, bufB, b2, W3, bufA, N);
    fgather4<<<cdiv(N, 64), 256, 0, stream>>>(row_ptr, pack, dis, bufA, b3, out, N);
}

// Round 12
// 444.176 us; speedup vs baseline: 7.6610x; 1.0124x over previous
//
#include <hip/hip_runtime.h>
#include <hip/hip_bf16.h>

// GCN 3-layer forward: x[N,128] -> GCNConv(64) -> leaky -> GCNConv(32) -> leaky
// -> GCNConv(4) -> softmax.  N=100000, E=3200000.
// Round 12: round-11 fused epilogues kept, but inline dis[src] (paid 3x, one per
// gather pass: fgather64 121->153us) reverted to a single k_norm premultiply
// pass (pack.y = dis[d]*w*dis[src], ~20us once). Gather loop unrolled x8.

#define BLK 256

// ---- Phase A: per-block LDS histogram over dst buckets (bucket = dst>>9) ----
__global__ __launch_bounds__(256) void k_hist(const int* __restrict__ dst,
                                              int* __restrict__ hist,
                                              int E, int CH, int NB) {
    __shared__ int h[256];
    int b = blockIdx.x, t = threadIdx.x;
    h[t] = 0;
    __syncthreads();
    int beg = b * CH, fin = min(E, beg + CH);
    for (int e = beg + t; e < fin; e += 256)
        atomicAdd(&h[dst[e] >> 9], 1);
    __syncthreads();
    if (t < NB) hist[t * 256 + b] = h[t];   // bucket-major layout
}

// ---- 3-kernel exclusive scan (n <= 512*256) ----
__global__ void k_scan1(const int* __restrict__ in, int* __restrict__ outv,
                        int* __restrict__ partials, int n) {
    __shared__ int sm[256];
    int i = blockIdx.x * 256 + threadIdx.x;
    int v = (i < n) ? in[i] : 0;
    sm[threadIdx.x] = v;
    __syncthreads();
    for (int off = 1; off < 256; off <<= 1) {
        int t = (threadIdx.x >= off) ? sm[threadIdx.x - off] : 0;
        __syncthreads();
        sm[threadIdx.x] += t;
        __syncthreads();
    }
    if (i < n) outv[i] = sm[threadIdx.x] - v;
    if (threadIdx.x == 255) partials[blockIdx.x] = sm[255];
}

__global__ void k_scan2(int* __restrict__ partials, int nb) {
    __shared__ int sm[512];
    int t = threadIdx.x;
    int v = (t < nb) ? partials[t] : 0;
    sm[t] = v;
    __syncthreads();
    for (int off = 1; off < 512; off <<= 1) {
        int x = (t >= off) ? sm[t - off] : 0;
        __syncthreads();
        sm[t] += x;
        __syncthreads();
    }
    if (t < nb) partials[t] = sm[t] - v;
}

__global__ void k_scan3(int* __restrict__ data, const int* __restrict__ partials, int n) {
    int i = blockIdx.x * 256 + threadIdx.x;
    if (i < n) data[i] += partials[i >> 8];
}

// ---- Phase C: scatter edges into bucket-sorted tmp ----
// record: x = (dlocal<<18) | src  (src < 2^18), y = w bits
__global__ __launch_bounds__(256) void k_bscatter(const int* __restrict__ src,
                                                  const int* __restrict__ dst,
                                                  const float* __restrict__ w,
                                                  const int* __restrict__ scanout,
                                                  int2* __restrict__ tmp,
                                                  int E, int CH, int NB) {
    __shared__ int cur[256];
    int b = blockIdx.x, t = threadIdx.x;
    if (t < NB) cur[t] = scanout[t * 256 + b];
    __syncthreads();
    int beg = b * CH, fin = min(E, beg + CH);
    for (int e = beg + t; e < fin; e += 256) {
        int d = dst[e];
        int q = d >> 9;
        int pos = atomicAdd(&cur[q], 1);             // LDS atomic
        tmp[pos] = make_int2(((d & 511) << 18) | src[e], __float_as_int(w[e]));
    }
}

// ---- Phase D: per-bucket CSR + fused dis = rsqrt(1 + sum_w) ----
__global__ __launch_bounds__(256) void k_bcsr(const int* __restrict__ scanout,
                                              const int2* __restrict__ tmp,
                                              int2* __restrict__ pack,
                                              int* __restrict__ row_ptr,
                                              float* __restrict__ dis,
                                              int n, int E, int NB) {
    __shared__ int cnt[512];
    __shared__ float wsum[512];
    __shared__ int psum[256];
    int q = blockIdx.x, t = threadIdx.x;
    int base = scanout[q * 256];
    int end  = (q == NB - 1) ? E : scanout[(q + 1) * 256];
    cnt[t] = 0; cnt[t + 256] = 0;
    wsum[t] = 0.f; wsum[t + 256] = 0.f;
    __syncthreads();
    for (int j = base + t; j < end; j += 256) {
        int2 r = tmp[j];
        int d = r.x >> 18;
        atomicAdd(&cnt[d], 1);
        atomicAdd(&wsum[d], __int_as_float(r.y));
    }
    __syncthreads();
    // exclusive scan of cnt[512] with 256 threads
    int a = cnt[2 * t], bb = cnt[2 * t + 1];
    psum[t] = a + bb;
    __syncthreads();
    for (int off = 1; off < 256; off <<= 1) {
        int v = (t >= off) ? psum[t - off] : 0;
        __syncthreads();
        psum[t] += v;
        __syncthreads();
    }
    int pex = psum[t] - (a + bb);
    __syncthreads();
    cnt[2 * t] = pex;                                // fill cursors
    cnt[2 * t + 1] = pex + a;
    int node0 = q * 512;
    if (node0 + 2 * t < n) {
        row_ptr[node0 + 2 * t] = base + pex;
        dis[node0 + 2 * t] = rsqrtf(1.f + wsum[2 * t]);
    }
    if (node0 + 2 * t + 1 < n) {
        row_ptr[node0 + 2 * t + 1] = base + pex + a;
        dis[node0 + 2 * t + 1] = rsqrtf(1.f + wsum[2 * t + 1]);
    }
    if (q == 0 && t == 0) row_ptr[n] = E;
    __syncthreads();
    for (int j = base + t; j < end; j += 256) {
        int2 r = tmp[j];
        int d = r.x >> 18;
        int pos = base + atomicAdd(&cnt[d], 1);      // LDS atomic
        pack[pos] = make_int2(r.x & 0x3FFFF, r.y);   // (src, w)
    }
}

// one wave per node: pack[j].y = dis[d] * w * dis[src]  (contiguous RMW, once)
__global__ __launch_bounds__(256) void k_norm(const int* __restrict__ rp,
                                              const float* __restrict__ dis,
                                              int2* __restrict__ pack, int n) {
    int node = blockIdx.x * 4 + (threadIdx.x >> 6);
    int lane = threadIdx.x & 63;
    if (node >= n) return;
    float dd = dis[node];
    int beg = rp[node], end = rp[node + 1];
    for (int j = beg + lane; j < end; j += 64) {
        int2 p = pack[j];
        p.y = __float_as_int(dd * __int_as_float(p.y) * dis[p.x]);
        pack[j] = p;
    }
}

__device__ __forceinline__ float leaky01(float v) {
    return v > 0.f ? v : 0.01f * v;
}

// gather core (premultiplied norm), unrolled x8 for MLP:
// acc = dis^2*h[node][c] + sum_j nm_j * h[src_j][c]
template<int F>
__device__ __forceinline__ float gather_acc(const int* __restrict__ rp,
                                            const int2* __restrict__ pack,
                                            const float* __restrict__ h,
                                            int node, int c, float dd) {
    float acc = dd * dd * h[(size_t)node * F + c];
    int beg = rp[node], end = rp[node + 1];
    int j = beg;
    for (; j + 8 <= end; j += 8) {
        int2 p[8];
        float hv[8];
#pragma unroll
        for (int u = 0; u < 8; ++u) p[u] = pack[j + u];
#pragma unroll
        for (int u = 0; u < 8; ++u) hv[u] = h[(size_t)p[u].x * F + c];
#pragma unroll
        for (int u = 0; u < 8; ++u) acc += __int_as_float(p[u].y) * hv[u];
    }
    for (; j < end; ++j) {
        int2 p = pack[j];
        acc += __int_as_float(p.y) * h[(size_t)p.x * F + c];
    }
    return acc;
}

// layer-1 agg + leaky(+b1) + W2 matmul -> h2[N,32].  One 64-lane wave per node.
__global__ __launch_bounds__(256) void fgather64(
        const int* __restrict__ rp, const int2* __restrict__ pack,
        const float* __restrict__ dis, const float* __restrict__ h,   // h1 [n,64]
        const float* __restrict__ b1, const float* __restrict__ W2,   // [32][64]
        float* __restrict__ h2out, int n) {
    __shared__ float sW2t[64 * 33];    // [c][c2], padded
    __shared__ float sact[4][64];
    int tid = threadIdx.x;
    for (int i = tid; i < 2048; i += 256)
        sW2t[(i & 63) * 33 + (i >> 6)] = W2[i];
    int w = tid >> 6, l = tid & 63;
    int node = blockIdx.x * 4 + w;
    bool valid = node < n;
    float act = 0.f;
    if (valid) {
        float dd = dis[node];
        float acc = gather_acc<64>(rp, pack, h, node, l, dd);
        act = leaky01(acc + b1[l]);
    }
    sact[w][l] = act;
    __syncthreads();
    if (valid) {
        int c2 = l & 31, half = l >> 5;
        float s = 0.f;
#pragma unroll 8
        for (int cc = 0; cc < 32; ++cc) {
            int c = half * 32 + cc;
            s += sW2t[c * 33 + c2] * sact[w][c];
        }
        s += __shfl_xor(s, 32);
        if (l < 32) h2out[(size_t)node * 32 + c2] = s;
    }
}

// layer-2 agg + leaky(+b2) + W3 matmul -> h3[N,4].  One 32-lane group per node.
__global__ __launch_bounds__(256) void fgather32(
        const int* __restrict__ rp, const int2* __restrict__ pack,
        const float* __restrict__ dis, const float* __restrict__ h,   // h2 [n,32]
        const float* __restrict__ b2, const float* __restrict__ W3,   // [4][32]
        float* __restrict__ h3out, int n) {
    __shared__ float sW3t[32 * 5];     // [c][c3], padded
    __shared__ float sact[8][32];
    int tid = threadIdx.x;
    if (tid < 128) sW3t[(tid & 31) * 5 + (tid >> 5)] = W3[tid];
    int w = tid >> 5, g = tid & 31;
    int node = blockIdx.x * 8 + w;
    bool valid = node < n;
    float act = 0.f;
    if (valid) {
        float dd = dis[node];
        float acc = gather_acc<32>(rp, pack, h, node, g, dd);
        act = leaky01(acc + b2[g]);
    }
    sact[w][g] = act;
    __syncthreads();
    if (valid) {
        int c3 = g & 3;
        float s = 0.f;
#pragma unroll
        for (int m = 0; m < 4; ++m) {
            int c = (g >> 2) + 8 * m;
            s += sW3t[c * 5 + c3] * sact[w][c];
        }
        s += __shfl_xor(s, 4, 32);
        s += __shfl_xor(s, 8, 32);
        s += __shfl_xor(s, 16, 32);
        if (g < 4) h3out[(size_t)node * 4 + g] = s;
    }
}

// layer-3 agg + b3 + softmax -> out[N,4].  One 4-lane group per node.
__global__ __launch_bounds__(256) void fgather4(
        const int* __restrict__ rp, const int2* __restrict__ pack,
        const float* __restrict__ dis, const float* __restrict__ h,   // h3 [n,4]
        const float* __restrict__ b3, float* __restrict__ out, int n) {
    int tid = threadIdx.x;
    int node = blockIdx.x * 64 + (tid >> 2);
    int c = tid & 3;
    if (node >= n) return;
    float dd = dis[node];
    float acc = gather_acc<4>(rp, pack, h, node, c, dd);
    float v = acc + b3[c];
    float m = fmaxf(v, __shfl_xor(v, 1, 4));
    m = fmaxf(m, __shfl_xor(m, 2, 4));
    float e = expf(v - m);
    float ssum = e + __shfl_xor(e, 1, 4);
    ssum += __shfl_xor(ssum, 2, 4);
    out[(size_t)node * 4 + c] = e / ssum;
}

// Tiled linear (layer 1 only): out[n][c] = sum_k in[n][k] * W[c][k].
template<int FIN, int FOUT, bool ACT>
__global__ __launch_bounds__(256) void k_linear(
        const float* __restrict__ in, const float* __restrict__ W,
        const float* __restrict__ bias_in, float* __restrict__ out, int n) {
    constexpr int TM = 64;
    constexpr int CPT = FOUT / 4;
    __shared__ __align__(16) float Wt[FIN * FOUT];
    __shared__ __align__(16) float xst[TM * FIN];

    const int tid = threadIdx.x;
    const int nb = blockIdx.x * TM;

    for (int i = tid; i < FIN * FOUT; i += 256) {
        int c = i / FIN, k = i % FIN;
        Wt[k * FOUT + c] = W[i];
    }
    __syncthreads();

    for (int i4 = tid; i4 < TM * FIN / 4; i4 += 256) {
        int idx = i4 * 4;
        int r = idx / FIN, k0 = idx % FIN;
        if (nb + r < n) {
            float4 v = *(const float4*)&in[(size_t)(nb + r) * FIN + k0];
            if (ACT) {
                float4 b = *(const float4*)&bias_in[k0];
                v.x = leaky01(v.x + b.x); v.y = leaky01(v.y + b.y);
                v.z = leaky01(v.z + b.z); v.w = leaky01(v.w + b.w);
            }
            xst[(k0 + 0) * TM + r] = v.x;
            xst[(k0 + 1) * TM + r] = v.y;
            xst[(k0 + 2) * TM + r] = v.z;
            xst[(k0 + 3) * TM + r] = v.w;
        }
    }
    __syncthreads();

    const int nl = tid >> 2;
    const int c0 = (tid & 3) * CPT;
    if (nb + nl >= n) return;

    float4 acc[CPT / 4];
#pragma unroll
    for (int j = 0; j < CPT / 4; ++j) acc[j] = make_float4(0.f, 0.f, 0.f, 0.f);
#pragma unroll 8
    for (int k = 0; k < FIN; ++k) {
        float xv = xst[k * TM + nl];
        const float4* wr = (const float4*)&Wt[k * FOUT + c0];
#pragma unroll
        for (int j = 0; j < CPT / 4; ++j) {
            float4 w4 = wr[j];
            acc[j].x += xv * w4.x; acc[j].y += xv * w4.y;
            acc[j].z += xv * w4.z; acc[j].w += xv * w4.w;
        }
    }
    float4* o = (float4*)&out[(size_t)(nb + nl) * FOUT + c0];
#pragma unroll
    for (int j = 0; j < CPT / 4; ++j) o[j] = acc[j];
}

static inline int cdiv(long long a, int b) { return (int)((a + b - 1) / b); }

extern "C" void kernel_launch(void* const* d_in, const int* in_sizes, int n_in,
                              void* d_out, int out_size, void* d_ws, size_t ws_size,
                              hipStream_t stream) {
    const float* x   = (const float*)d_in[0];
    const int*   ei  = (const int*)d_in[1];
    const float* ew  = (const float*)d_in[2];
    const float* W1  = (const float*)d_in[3];
    const float* b1  = (const float*)d_in[4];
    const float* W2  = (const float*)d_in[5];
    const float* b2  = (const float*)d_in[6];
    const float* W3  = (const float*)d_in[7];
    const float* b3  = (const float*)d_in[8];
    float* out = (float*)d_out;

    const int N = in_sizes[0] / 128;
    const int E = in_sizes[2];
    const int* src = ei;
    const int* dst = ei + E;

    const int NB = (N + 511) >> 9;          // buckets of 512 nodes
    const int GB = 256;
    const int CH = cdiv(E, GB);
    const int n_scan = NB * GB;

    char* base = (char*)d_ws;
    auto alloc = [&](size_t bytes) {
        char* p = base;
        base += (bytes + 255) & ~(size_t)255;
        return p;
    };
    float* dis      = (float*)alloc((size_t)N * 4);
    int*   row_ptr  = (int*)  alloc(((size_t)N + 1) * 4);
    int*   hist     = (int*)  alloc((size_t)n_scan * 4);
    int*   scanout  = (int*)  alloc((size_t)n_scan * 4);
    int*   partials = (int*)  alloc(512 * 4);
    int2*  pack     = (int2*) alloc((size_t)E * 8);
    float* bufA     = (float*)alloc((size_t)N * 64 * 4);
    float* bufB     = (float*)alloc((size_t)N * 64 * 4);
    int2*  tmp      = (int2*)bufA;          // aliases bufA (dead after k_bcsr)

    // --- CSR build via bucket sort; dis fused into k_bcsr; norm premult once ---
    k_hist<<<GB, 256, 0, stream>>>(dst, hist, E, CH, NB);
    k_scan1<<<cdiv(n_scan, 256), 256, 0, stream>>>(hist, scanout, partials, n_scan);
    k_scan2<<<1, 512, 0, stream>>>(partials, cdiv(n_scan, 256));
    k_scan3<<<cdiv(n_scan, 256), 256, 0, stream>>>(scanout, partials, n_scan);
    k_bscatter<<<GB, 256, 0, stream>>>(src, dst, ew, scanout, tmp, E, CH, NB);
    k_bcsr<<<NB, 256, 0, stream>>>(scanout, tmp, pack, row_ptr, dis, N, E, NB);
    k_norm<<<cdiv(N, 4), 256, 0, stream>>>(row_ptr, dis, pack, N);

    // --- fused layers ---
    k_linear<128, 64, false><<<cdiv(N, 64), 256, 0, stream>>>(x, W1, nullptr, bufA, N);
    fgather64<<<cdiv(N, 4), 256, 0, stream>>>(row_ptr, pack, dis, bufA, b1, W2, bufB, N);
    fgather32<<<cdiv(N, 8), 256, 0, stream>>>(row_ptr, pack, dis, bufB, b2, W3, bufA, N);
    fgather4<<<cdiv(N, 64), 256, 0, stream>>>(row_ptr, pack, dis, bufA, b3, out, N);
}